// Round 14
// baseline (192.259 us; speedup 1.0000x reference)
//
#include <hip/hip_runtime.h>

#define N_NODES 50000
#define N_EDGES 600000
#define D 128
#define N_RELS 460
#define CAP_LOG 6            // 64 CSR slots per node (max degree ~35 for Poisson(12))

typedef unsigned short u16;
typedef __attribute__((ext_vector_type(8))) short bf16x8;   // 8 bf16 (4 VGPRs)
typedef __attribute__((ext_vector_type(4))) float f32x4;

// workspace layout (element offsets, 4-byte elements)
enum : int {
    OFF_W      = 0,          //   384 floats  (w = fc1^T @ fc2^T, split w1|w2|w3)
    OFF_S1     = 384,        // 50000 floats
    OFF_S2     = 50384,      // 50000 floats
    OFF_S3     = 100384,     //   460 floats + pad
    OFF_COUNTS = 100864,     // 50000*16 ints (one counter per 64B line)
    OFF_CSR    = 900864,     // 50000*64 uints (padded CSR: src(16b) | typ(16b))
    OFF_HB     = 4100864,    // 6400000 bf16 = 3200000 float slots (h in bf16)
};                           // total ~27.9 MiB

#define NODE_WAVES   12500   // 4 rows per wave
#define REL_WAVES    115     // 460 rels, 4 per wave
#define SCORE_BLOCKS 3154    // ceil((NODE_WAVES+REL_WAVES)/4)
#define ZERO_BLOCKS  196     // 196*256 threads * 4 int4 >= 200000 int4
#define FILL_BLOCKS  293     // ceil(75000/256): 8 edges per thread
#define GG_BLOCKS    782     // ceil(50000/64): gather+gemm, 64 nodes/block
#define WT_STRIDE    136     // LDS row stride (bf16 elems): 272B, 16B-aligned b128

__device__ __forceinline__ u16 f2bf(float f) {
    unsigned u = __float_as_uint(f);
    unsigned r = u + 0x7FFFu + ((u >> 16) & 1u);   // RNE
    return (u16)(r >> 16);
}
__device__ __forceinline__ float blo(unsigned u) { return __uint_as_float(u << 16); }
__device__ __forceinline__ float bhi(unsigned u) { return __uint_as_float(u & 0xFFFF0000u); }

// ---------- K0: tiny prep — {zero line-padded counters} + {w vector} ----------
__global__ void k_prep(const float* __restrict__ fc1, const float* __restrict__ fc2,
                       float* __restrict__ w, int* __restrict__ counts) {
    int b = blockIdx.x, t = threadIdx.x;
    if (b == 0) {
        for (int j = t; j < 3 * D; j += 256) {
            float acc = 0.f;
            for (int k = 0; k < D; ++k) acc += fc2[k] * fc1[k * 3 * D + j];
            w[j] = acc;
        }
    } else {
        int i4 = (b - 1) * 256 + t;
        #pragma unroll
        for (int rep = 0; rep < 4; ++rep) {
            int idx = i4 * 4 + rep;
            if (idx * 4 < N_NODES * 16)
                ((int4*)counts)[idx] = make_int4(0, 0, 0, 0);
        }
    }
}

// ---------- K1: fused {atomic CSR fill, 8 edges/thread} + {scores + bf16 cast} ----------
__global__ __launch_bounds__(256) void k_fused(
        const int* __restrict__ src, const int* __restrict__ dst,
        const int* __restrict__ typ, int* __restrict__ counts,
        unsigned* __restrict__ csr,
        const float* __restrict__ h, const float* __restrict__ emb_rel,
        const float* __restrict__ w,
        float* __restrict__ s1, float* __restrict__ s2, float* __restrict__ s3,
        u16* __restrict__ hb) {
    if (blockIdx.x < FILL_BLOCKS) {
        // ---- CSR fill with line-padded atomic rank: 8 independent chains/thread ----
        int i = blockIdx.x * blockDim.x + threadIdx.x;
        if (i >= N_EDGES / 8) return;
        int4 da = ((const int4*)dst)[2 * i],     db = ((const int4*)dst)[2 * i + 1];
        int4 sa = ((const int4*)src)[2 * i],     sb = ((const int4*)src)[2 * i + 1];
        int4 ta = ((const int4*)typ)[2 * i],     tb = ((const int4*)typ)[2 * i + 1];
        int l0 = atomicAdd(&counts[da.x << 4], 1);
        int l1 = atomicAdd(&counts[da.y << 4], 1);
        int l2 = atomicAdd(&counts[da.z << 4], 1);
        int l3 = atomicAdd(&counts[da.w << 4], 1);
        int l4 = atomicAdd(&counts[db.x << 4], 1);
        int l5 = atomicAdd(&counts[db.y << 4], 1);
        int l6 = atomicAdd(&counts[db.z << 4], 1);
        int l7 = atomicAdd(&counts[db.w << 4], 1);
        csr[(da.x << CAP_LOG) + l0] = (unsigned)sa.x | ((unsigned)ta.x << 16);
        csr[(da.y << CAP_LOG) + l1] = (unsigned)sa.y | ((unsigned)ta.y << 16);
        csr[(da.z << CAP_LOG) + l2] = (unsigned)sa.z | ((unsigned)ta.z << 16);
        csr[(da.w << CAP_LOG) + l3] = (unsigned)sa.w | ((unsigned)ta.w << 16);
        csr[(db.x << CAP_LOG) + l4] = (unsigned)sb.x | ((unsigned)tb.x << 16);
        csr[(db.y << CAP_LOG) + l5] = (unsigned)sb.y | ((unsigned)tb.y << 16);
        csr[(db.z << CAP_LOG) + l6] = (unsigned)sb.z | ((unsigned)tb.z << 16);
        csr[(db.w << CAP_LOG) + l7] = (unsigned)sb.w | ((unsigned)tb.w << 16);
    } else {
        // ---- node scores (4 rows/wave) + bf16 cast of h; rel s3 ----
        int wv = ((blockIdx.x - FILL_BLOCKS) * blockDim.x + threadIdx.x) >> 6;
        int l  = threadIdx.x & 63;
        int sub = l >> 4;                     // which of the wave's 4 rows
        int q   = l & 15;                     // 16 lanes x 8 floats = 128 floats/row
        if (wv < NODE_WAVES) {
            int r = wv * 4 + sub;
            const float* hp = h + (size_t)r * D + q * 8;
            float4 h0 = *(const float4*)hp;
            float4 h1 = *(const float4*)(hp + 4);
            uint4 pk;
            pk.x = (unsigned)f2bf(h0.x) | ((unsigned)f2bf(h0.y) << 16);
            pk.y = (unsigned)f2bf(h0.z) | ((unsigned)f2bf(h0.w) << 16);
            pk.z = (unsigned)f2bf(h1.x) | ((unsigned)f2bf(h1.y) << 16);
            pk.w = (unsigned)f2bf(h1.z) | ((unsigned)f2bf(h1.w) << 16);
            ((uint4*)hb)[(size_t)r * 16 + q] = pk;        // 16B/lane coalesced
            float4 w10 = *(const float4*)(w + q * 8);
            float4 w11 = *(const float4*)(w + q * 8 + 4);
            float4 w20 = *(const float4*)(w + D + q * 8);
            float4 w21 = *(const float4*)(w + D + q * 8 + 4);
            float a1 = h0.x * w10.x + h0.y * w10.y + h0.z * w10.z + h0.w * w10.w
                     + h1.x * w11.x + h1.y * w11.y + h1.z * w11.z + h1.w * w11.w;
            float a2 = h0.x * w20.x + h0.y * w20.y + h0.z * w20.z + h0.w * w20.w
                     + h1.x * w21.x + h1.y * w21.y + h1.z * w21.z + h1.w * w21.w;
            #pragma unroll
            for (int o = 8; o; o >>= 1) { a1 += __shfl_xor(a1, o, 16); a2 += __shfl_xor(a2, o, 16); }
            if (q == 0) { s1[r] = a1; s2[r] = a2; }
        } else if (wv < NODE_WAVES + REL_WAVES) {
            int r = (wv - NODE_WAVES) * 4 + sub;          // 460 = 115*4 exact
            const float* rp = emb_rel + (size_t)r * D + q * 8;
            float4 r0 = *(const float4*)rp;
            float4 r1 = *(const float4*)(rp + 4);
            float4 w30 = *(const float4*)(w + 2 * D + q * 8);
            float4 w31 = *(const float4*)(w + 2 * D + q * 8 + 4);
            float a3 = r0.x * w30.x + r0.y * w30.y + r0.z * w30.z + r0.w * w30.w
                     + r1.x * w31.x + r1.y * w31.y + r1.z * w31.z + r1.w * w31.w;
            #pragma unroll
            for (int o = 8; o; o >>= 1) a3 += __shfl_xor(a3, o, 16);
            if (q == 0) s3[r] = a3;
        }
    }
}

#define ROWACC(uu, cc)                                                         \
    accA.x += (cc) * blo((uu).x);  accA.y += (cc) * bhi((uu).x);               \
    accA.z += (cc) * blo((uu).y);  accA.w += (cc) * bhi((uu).y);               \
    accB.x += (cc) * blo((uu).z);  accB.y += (cc) * bhi((uu).z);               \
    accB.z += (cc) * blo((uu).w);  accB.w += (cc) * bhi((uu).w);

// ---------- K2: fused {MFMA self-loop GEMM} + {softmax gather}; single out write ----------
// 64 nodes/block. Phase A: stage W->bf16^T in LDS. Phase B: MFMA h@W from hb (A-frag:
// A[m=lane&15][k=quad*8+j]; C/D: D[m=quad*4+reg][n=lane&15]). Phase C: park result in
// LDS (reuse W buffer). Phase D: per-16-lane-group gather of 4 nodes; out = base+agg/den.
__global__ __launch_bounds__(256) void k_gather_gemm(
        const float* __restrict__ W, const u16* __restrict__ hb,
        const int* __restrict__ counts, const unsigned* __restrict__ csr,
        const float* __restrict__ s1, const float* __restrict__ s2,
        const float* __restrict__ s3, float* __restrict__ out) {
    __shared__ u16 Ws[D * WT_STRIDE];                   // 34 KiB; reused for fp32 result
    float* LDSf = (float*)Ws;                           // 64*128 fp32 = 32 KiB
    int t = threadIdx.x;

    // ---- Phase A: stage W transposed bf16 ----
    for (int i = t; i < (D * D) / 4; i += 256) {        // 4096 float4-units
        float4 v = ((const float4*)W)[i];
        int k  = i >> 5;                                // 32 float4 per row
        int n0 = (i & 31) * 4;
        Ws[(n0 + 0) * WT_STRIDE + k] = f2bf(v.x);
        Ws[(n0 + 1) * WT_STRIDE + k] = f2bf(v.y);
        Ws[(n0 + 2) * WT_STRIDE + k] = f2bf(v.z);
        Ws[(n0 + 3) * WT_STRIDE + k] = f2bf(v.w);
    }
    __syncthreads();

    // ---- Phase B: MFMA h@W (A from hb) ----
    int wave = t >> 6, lane = t & 63;
    int quad = lane >> 4, m16 = lane & 15;
    int nbase = blockIdx.x * 64 + wave * 16;

    f32x4 acc[8];
    #pragma unroll
    for (int cg = 0; cg < 8; ++cg) acc[cg] = (f32x4){0.f, 0.f, 0.f, 0.f};

    int arow = nbase + m16;
    if (arow >= N_NODES) arow = N_NODES - 1;            // clamp; result unused
    const u16* aptr = hb + (size_t)arow * D + quad * 8;

    #pragma unroll
    for (int k0 = 0; k0 < D; k0 += 32) {
        bf16x8 a = *(const bf16x8*)(aptr + k0);
        #pragma unroll
        for (int cg = 0; cg < 8; ++cg) {
            bf16x8 bb = *(const bf16x8*)(&Ws[(cg * 16 + m16) * WT_STRIDE + k0 + quad * 8]);
            acc[cg] = __builtin_amdgcn_mfma_f32_16x16x32_bf16(a, bb, acc[cg], 0, 0, 0);
        }
    }
    __syncthreads();                                    // all MFMA reads of Ws done

    // ---- Phase C: park gemm result in LDS (row-local, col) ----
    #pragma unroll
    for (int reg = 0; reg < 4; ++reg) {
        int lrow = wave * 16 + quad * 4 + reg;          // 0..63
        #pragma unroll
        for (int cg = 0; cg < 8; ++cg)
            LDSf[lrow * D + cg * 16 + m16] = acc[cg][reg];
    }
    __syncthreads();

    // ---- Phase D: gather, 16-lane group per node, 4 nodes per group ----
    int g  = t >> 4;                                    // 0..15
    int gl = t & 15;
    for (int k = 0; k < 4; ++k) {
        int ln = g * 4 + k;                             // 0..63
        int n  = blockIdx.x * 64 + ln;
        if (n >= N_NODES) continue;
        int deg = counts[n << 4];
        float* op = out + (size_t)n * D + gl * 8;
        f32x4 base0 = *(f32x4*)(&LDSf[ln * D + gl * 8]);
        f32x4 base1 = *(f32x4*)(&LDSf[ln * D + gl * 8 + 4]);
        if (deg == 0) {                                 // no edges: out = h@W only
            *(f32x4*)op = base0;
            *(f32x4*)(op + 4) = base1;
            continue;
        }
        int beg = n << CAP_LOG;
        int end = beg + deg;
        float s2n = s2[n];
        float den = 0.f;
        f32x4 accA = {0.f, 0.f, 0.f, 0.f}, accB = {0.f, 0.f, 0.f, 0.f};

        for (int cb = beg; cb < end; cb += 16) {
            int i = cb + gl;
            int msrc = 0; float mex = 0.f;
            if (i < end) {
                unsigned p = csr[i];
                msrc = (int)(p & 0xFFFFu);
                float x = s1[msrc] + s2n + s3[p >> 16];
                float lv = (x > 0.f) ? x : 0.01f * x;
                mex = __expf(lv);                       // |x| small; shift-invariant
            }
            den += mex;
            int cnt = min(16, end - cb);
            int j = 0;
            for (; j + 7 < cnt; j += 8) {               // 8 loads in flight
                int aa[8]; float cc[8]; uint4 uu[8];
                #pragma unroll
                for (int u = 0; u < 8; ++u) {
                    aa[u] = __shfl(msrc, j + u, 16);
                    cc[u] = __shfl(mex,  j + u, 16);
                }
                #pragma unroll
                for (int u = 0; u < 8; ++u)
                    uu[u] = ((const uint4*)(hb + (size_t)aa[u] * D))[gl];
                #pragma unroll
                for (int u = 0; u < 8; ++u) { ROWACC(uu[u], cc[u]); }
            }
            for (; j + 3 < cnt; j += 4) {
                int aa[4]; float cc[4]; uint4 uu[4];
                #pragma unroll
                for (int u = 0; u < 4; ++u) {
                    aa[u] = __shfl(msrc, j + u, 16);
                    cc[u] = __shfl(mex,  j + u, 16);
                }
                #pragma unroll
                for (int u = 0; u < 4; ++u)
                    uu[u] = ((const uint4*)(hb + (size_t)aa[u] * D))[gl];
                #pragma unroll
                for (int u = 0; u < 4; ++u) { ROWACC(uu[u], cc[u]); }
            }
            for (; j < cnt; ++j) {
                int   a0 = __shfl(msrc, j, 16);
                float c0 = __shfl(mex, j, 16);
                uint4 u0 = ((const uint4*)(hb + (size_t)a0 * D))[gl];
                ROWACC(u0, c0);
            }
        }
        #pragma unroll
        for (int o = 8; o; o >>= 1) den += __shfl_xor(den, o, 16);
        float inv = 1.f / den;

        *(f32x4*)op       = base0 + accA * inv;         // single out write
        *(f32x4*)(op + 4) = base1 + accB * inv;
    }
}

extern "C" void kernel_launch(void* const* d_in, const int* in_sizes, int n_in,
                              void* d_out, int out_size, void* d_ws, size_t ws_size,
                              hipStream_t stream) {
    const float* h       = (const float*)d_in[0];
    const float* emb_rel = (const float*)d_in[1];
    const float* fc1     = (const float*)d_in[2];   // [D, 3D]
    const float* fc2     = (const float*)d_in[3];   // [1, D]
    const float* loopw   = (const float*)d_in[4];   // [D, D]
    const int*   esrc    = (const int*)d_in[5];
    const int*   edst    = (const int*)d_in[6];
    const int*   etyp    = (const int*)d_in[7];
    float* out = (float*)d_out;
    float* ws  = (float*)d_ws;

    float*    w       = ws + OFF_W;
    float*    s1      = ws + OFF_S1;
    float*    s2      = ws + OFF_S2;
    float*    s3      = ws + OFF_S3;
    int*      counts  = (int*)(ws + OFF_COUNTS);
    unsigned* csr     = (unsigned*)(ws + OFF_CSR);
    u16*      hb      = (u16*)(ws + OFF_HB);

    // 1: tiny prep — zero counters + w vector
    k_prep<<<1 + ZERO_BLOCKS, 256, 0, stream>>>(fc1, fc2, w, counts);

    // 2: fused atomic CSR fill (8 edges/thread) + scores + bf16 cast
    k_fused<<<FILL_BLOCKS + SCORE_BLOCKS, 256, 0, stream>>>(
        esrc, edst, etyp, counts, csr, h, emb_rel, w, s1, s2, s3, hb);

    // 3: fused MFMA self-loop GEMM + softmax gather (single out write)
    k_gather_gemm<<<GG_BLOCKS, 256, 0, stream>>>(
        loopw, hb, counts, csr, s1, s2, s3, out);
}

// Round 15
// 165.140 us; speedup vs baseline: 1.1642x; 1.1642x over previous
//
#include <hip/hip_runtime.h>

#define N_NODES 50000
#define N_EDGES 600000
#define D 128
#define N_RELS 460
#define CAP_LOG 6            // 64 CSR slots per node (max degree ~35 for Poisson(12))

typedef unsigned short u16;
typedef __attribute__((ext_vector_type(8))) short bf16x8;   // 8 bf16 (4 VGPRs)
typedef __attribute__((ext_vector_type(4))) float f32x4;

// workspace layout (element offsets, 4-byte elements)
enum : int {
    OFF_W      = 0,          //   384 floats  (w = fc1^T @ fc2^T, split w1|w2|w3)
    OFF_S1     = 384,        // 50000 floats
    OFF_S2     = 50384,      // 50000 floats
    OFF_S3     = 100384,     //   460 floats + pad
    OFF_COUNTS = 100864,     // 50000*16 ints (one counter per 64B line)
    OFF_CSR    = 900864,     // 50000*64 uints (padded CSR: src(16b) | typ(16b))
    OFF_HB     = 4100864,    // 6400000 bf16 = 3200000 float slots (h in bf16)
};                           // total ~27.9 MiB

#define NODE_WAVES   12500   // 4 rows per wave
#define REL_WAVES    115     // 460 rels, 4 per wave
#define SCORE_BLOCKS 3154    // ceil((NODE_WAVES+REL_WAVES)/4)
#define GEMM_BLOCKS  782     // ceil(50000/64)
#define ZERO_BLOCKS  196     // 196*256 threads * 4 int4 >= 200000 int4
#define FILL_BLOCKS  293     // ceil(75000/256): 8 edges per thread
#define WT_STRIDE    136     // LDS row stride (bf16 elems): 272B, 16B-aligned b128

__device__ __forceinline__ u16 f2bf(float f) {
    unsigned u = __float_as_uint(f);
    unsigned r = u + 0x7FFFu + ((u >> 16) & 1u);   // RNE
    return (u16)(r >> 16);
}
__device__ __forceinline__ float blo(unsigned u) { return __uint_as_float(u << 16); }
__device__ __forceinline__ float bhi(unsigned u) { return __uint_as_float(u & 0xFFFF0000u); }

// ---------- K0: prep — {MFMA self-loop GEMM + bf16 cast emit} + {zero counters} + {w} ----------
// gemm: out = h @ loop_weight via bf16 MFMA; the bf16 A-fragments are stored to hb
//       (free cast: conversion already needed for MFMA).
//       A-frag: A[m=lane&15][k=quad*8+j]; B-frag: B[k=quad*8+j][n=lane&15];
//       C/D: D[m=quad*4+reg][n=lane&15].
__global__ __launch_bounds__(256) void k_prep(
        const float* __restrict__ fc1, const float* __restrict__ fc2,
        const float* __restrict__ W, const float* __restrict__ h,
        float* __restrict__ w, int* __restrict__ counts,
        u16* __restrict__ hb, float* __restrict__ out) {
    __shared__ u16 Ws[D * WT_STRIDE];                   // 34 KiB
    int t = threadIdx.x;
    if (blockIdx.x < GEMM_BLOCKS) {
        // stage W transposed: Ws[n*136 + k] = bf16(W[k][n])
        for (int i = t; i < (D * D) / 4; i += 256) {    // 4096 float4-units
            float4 v = ((const float4*)W)[i];
            int k  = i >> 5;                            // 32 float4 per row
            int n0 = (i & 31) * 4;
            Ws[(n0 + 0) * WT_STRIDE + k] = f2bf(v.x);
            Ws[(n0 + 1) * WT_STRIDE + k] = f2bf(v.y);
            Ws[(n0 + 2) * WT_STRIDE + k] = f2bf(v.z);
            Ws[(n0 + 3) * WT_STRIDE + k] = f2bf(v.w);
        }
        __syncthreads();

        int wave = t >> 6, lane = t & 63;
        int quad = lane >> 4, m16 = lane & 15;
        int nbase = blockIdx.x * 64 + wave * 16;

        f32x4 acc[8];
        #pragma unroll
        for (int cg = 0; cg < 8; ++cg) acc[cg] = (f32x4){0.f, 0.f, 0.f, 0.f};

        int arow = nbase + m16;
        if (arow >= N_NODES) arow = N_NODES - 1;        // clamp; dup hb writes benign
        const float* aptr = h + (size_t)arow * D + quad * 8;
        u16* hbp = hb + (size_t)arow * D + quad * 8;

        #pragma unroll
        for (int k0 = 0; k0 < D; k0 += 32) {
            float4 a0 = *(const float4*)(aptr + k0);
            float4 a1 = *(const float4*)(aptr + k0 + 4);
            bf16x8 a;
            a[0] = (short)f2bf(a0.x); a[1] = (short)f2bf(a0.y);
            a[2] = (short)f2bf(a0.z); a[3] = (short)f2bf(a0.w);
            a[4] = (short)f2bf(a1.x); a[5] = (short)f2bf(a1.y);
            a[6] = (short)f2bf(a1.z); a[7] = (short)f2bf(a1.w);
            *(bf16x8*)(hbp + k0) = a;                   // free bf16 cast emit (16B)
            #pragma unroll
            for (int cg = 0; cg < 8; ++cg) {
                bf16x8 bb = *(const bf16x8*)(&Ws[(cg * 16 + m16) * WT_STRIDE + k0 + quad * 8]);
                acc[cg] = __builtin_amdgcn_mfma_f32_16x16x32_bf16(a, bb, acc[cg], 0, 0, 0);
            }
        }
        #pragma unroll
        for (int reg = 0; reg < 4; ++reg) {
            int row = nbase + quad * 4 + reg;
            if (row < N_NODES) {
                #pragma unroll
                for (int cg = 0; cg < 8; ++cg)
                    out[(size_t)row * D + cg * 16 + m16] = acc[cg][reg];
            }
        }
    } else if (blockIdx.x < GEMM_BLOCKS + ZERO_BLOCKS) {
        // zero 800000 line-padded counters via 4 int4/thread
        int i4 = (blockIdx.x - GEMM_BLOCKS) * 256 + t;
        #pragma unroll
        for (int rep = 0; rep < 4; ++rep) {
            int idx = i4 * 4 + rep;
            if (idx * 4 < N_NODES * 16)
                ((int4*)counts)[idx] = make_int4(0, 0, 0, 0);
        }
    } else {
        // w[j] = sum_k fc2[k] * fc1[k][j]
        for (int j = t; j < 3 * D; j += 256) {
            float acc = 0.f;
            for (int k = 0; k < D; ++k) acc += fc2[k] * fc1[k * 3 * D + j];
            w[j] = acc;
        }
    }
}

// ---------- K1: fused {atomic CSR fill, 8 edges/thread} + {scores from bf16 hb} ----------
__global__ __launch_bounds__(256) void k_fused(
        const int* __restrict__ src, const int* __restrict__ dst,
        const int* __restrict__ typ, int* __restrict__ counts,
        unsigned* __restrict__ csr,
        const u16* __restrict__ hb, const float* __restrict__ emb_rel,
        const float* __restrict__ w,
        float* __restrict__ s1, float* __restrict__ s2, float* __restrict__ s3) {
    if (blockIdx.x < FILL_BLOCKS) {
        // ---- CSR fill with line-padded atomic rank: 8 independent chains/thread ----
        int i = blockIdx.x * blockDim.x + threadIdx.x;
        if (i >= N_EDGES / 8) return;
        int4 da = ((const int4*)dst)[2 * i],     db = ((const int4*)dst)[2 * i + 1];
        int4 sa = ((const int4*)src)[2 * i],     sb = ((const int4*)src)[2 * i + 1];
        int4 ta = ((const int4*)typ)[2 * i],     tb = ((const int4*)typ)[2 * i + 1];
        int l0 = atomicAdd(&counts[da.x << 4], 1);
        int l1 = atomicAdd(&counts[da.y << 4], 1);
        int l2 = atomicAdd(&counts[da.z << 4], 1);
        int l3 = atomicAdd(&counts[da.w << 4], 1);
        int l4 = atomicAdd(&counts[db.x << 4], 1);
        int l5 = atomicAdd(&counts[db.y << 4], 1);
        int l6 = atomicAdd(&counts[db.z << 4], 1);
        int l7 = atomicAdd(&counts[db.w << 4], 1);
        csr[(da.x << CAP_LOG) + l0] = (unsigned)sa.x | ((unsigned)ta.x << 16);
        csr[(da.y << CAP_LOG) + l1] = (unsigned)sa.y | ((unsigned)ta.y << 16);
        csr[(da.z << CAP_LOG) + l2] = (unsigned)sa.z | ((unsigned)ta.z << 16);
        csr[(da.w << CAP_LOG) + l3] = (unsigned)sa.w | ((unsigned)ta.w << 16);
        csr[(db.x << CAP_LOG) + l4] = (unsigned)sb.x | ((unsigned)tb.x << 16);
        csr[(db.y << CAP_LOG) + l5] = (unsigned)sb.y | ((unsigned)tb.y << 16);
        csr[(db.z << CAP_LOG) + l6] = (unsigned)sb.z | ((unsigned)tb.z << 16);
        csr[(db.w << CAP_LOG) + l7] = (unsigned)sb.w | ((unsigned)tb.w << 16);
    } else {
        // ---- node scores from bf16 hb (4 rows/wave); rel s3 from fp32 emb_rel ----
        int wv = ((blockIdx.x - FILL_BLOCKS) * blockDim.x + threadIdx.x) >> 6;
        int l  = threadIdx.x & 63;
        int sub = l >> 4;                     // which of the wave's 4 rows
        int q   = l & 15;                     // 16 lanes x 8 elems = 128/row
        if (wv < NODE_WAVES) {
            int r = wv * 4 + sub;
            uint4 pk = ((const uint4*)hb)[(size_t)r * 16 + q];   // 8 bf16
            float4 w10 = *(const float4*)(w + q * 8);
            float4 w11 = *(const float4*)(w + q * 8 + 4);
            float4 w20 = *(const float4*)(w + D + q * 8);
            float4 w21 = *(const float4*)(w + D + q * 8 + 4);
            float a1 = blo(pk.x) * w10.x + bhi(pk.x) * w10.y
                     + blo(pk.y) * w10.z + bhi(pk.y) * w10.w
                     + blo(pk.z) * w11.x + bhi(pk.z) * w11.y
                     + blo(pk.w) * w11.z + bhi(pk.w) * w11.w;
            float a2 = blo(pk.x) * w20.x + bhi(pk.x) * w20.y
                     + blo(pk.y) * w20.z + bhi(pk.y) * w20.w
                     + blo(pk.z) * w21.x + bhi(pk.z) * w21.y
                     + blo(pk.w) * w21.z + bhi(pk.w) * w21.w;
            #pragma unroll
            for (int o = 8; o; o >>= 1) { a1 += __shfl_xor(a1, o, 16); a2 += __shfl_xor(a2, o, 16); }
            if (q == 0) { s1[r] = a1; s2[r] = a2; }
        } else if (wv < NODE_WAVES + REL_WAVES) {
            int r = (wv - NODE_WAVES) * 4 + sub;          // 460 = 115*4 exact
            const float* rp = emb_rel + (size_t)r * D + q * 8;
            float4 r0 = *(const float4*)rp;
            float4 r1 = *(const float4*)(rp + 4);
            float4 w30 = *(const float4*)(w + 2 * D + q * 8);
            float4 w31 = *(const float4*)(w + 2 * D + q * 8 + 4);
            float a3 = r0.x * w30.x + r0.y * w30.y + r0.z * w30.z + r0.w * w30.w
                     + r1.x * w31.x + r1.y * w31.y + r1.z * w31.z + r1.w * w31.w;
            #pragma unroll
            for (int o = 8; o; o >>= 1) a3 += __shfl_xor(a3, o, 16);
            if (q == 0) s3[r] = a3;
        }
    }
}

#define ROWACC(uu, cc)                                                         \
    accA.x += (cc) * blo((uu).x);  accA.y += (cc) * bhi((uu).x);               \
    accA.z += (cc) * blo((uu).y);  accA.w += (cc) * bhi((uu).y);               \
    accB.x += (cc) * blo((uu).z);  accB.y += (cc) * bhi((uu).z);               \
    accB.z += (cc) * blo((uu).w);  accB.w += (cc) * bhi((uu).w);

// ---------- K2: single-pass gather — on-the-fly exp, normalize at end ----------
// Tail-free inner loop: lanes with i>=end carry msrc=0/mex=0, so the window count
// can be rounded up to a multiple of 4 (padded entries add 0 * row0, cached).
__global__ void k_gather(const u16* __restrict__ hb, const int* __restrict__ counts,
                         const unsigned* __restrict__ csr,
                         const float* __restrict__ s1, const float* __restrict__ s2,
                         const float* __restrict__ s3, float* __restrict__ out) {
    int n  = (blockIdx.x * blockDim.x + threadIdx.x) >> 4;
    int gl = threadIdx.x & 15;
    if (n >= N_NODES) return;
    int deg = counts[n << 4];
    if (deg == 0) return;                                // deg 0: out = h@W only
    int beg = n << CAP_LOG;
    int end = beg + deg;

    float s2n = s2[n];
    float den = 0.f;
    f32x4 accA = {0.f, 0.f, 0.f, 0.f}, accB = {0.f, 0.f, 0.f, 0.f};

    for (int cb = beg; cb < end; cb += 16) {
        int i = cb + gl;
        int msrc = 0; float mex = 0.f;
        if (i < end) {
            unsigned p = csr[i];
            msrc = (int)(p & 0xFFFFu);
            float x = s1[msrc] + s2n + s3[p >> 16];
            float lv = (x > 0.f) ? x : 0.01f * x;
            mex = __expf(lv);                            // |x| small; shift-invariant
        }
        den += mex;                                      // lane-local; reduced at end
        int cnt  = min(16, end - cb);
        int cntr = (cnt + 3) & ~3;                       // round up: tail-free
        int j = 0;
        for (; j + 7 < cntr; j += 8) {                   // 8 loads in flight
            int aa[8]; float cc[8]; uint4 uu[8];
            #pragma unroll
            for (int u = 0; u < 8; ++u) {
                aa[u] = __shfl(msrc, j + u, 16);
                cc[u] = __shfl(mex,  j + u, 16);
            }
            #pragma unroll
            for (int u = 0; u < 8; ++u)
                uu[u] = ((const uint4*)(hb + (size_t)aa[u] * D))[gl];
            #pragma unroll
            for (int u = 0; u < 8; ++u) { ROWACC(uu[u], cc[u]); }
        }
        for (; j < cntr; j += 4) {
            int aa[4]; float cc[4]; uint4 uu[4];
            #pragma unroll
            for (int u = 0; u < 4; ++u) {
                aa[u] = __shfl(msrc, j + u, 16);
                cc[u] = __shfl(mex,  j + u, 16);
            }
            #pragma unroll
            for (int u = 0; u < 4; ++u)
                uu[u] = ((const uint4*)(hb + (size_t)aa[u] * D))[gl];
            #pragma unroll
            for (int u = 0; u < 4; ++u) { ROWACC(uu[u], cc[u]); }
        }
    }
    #pragma unroll
    for (int o = 8; o; o >>= 1) den += __shfl_xor(den, o, 16);
    float inv = 1.f / den;

    // non-temporal RMW of out: don't evict hot hb from L2
    f32x4* op = (f32x4*)(out + (size_t)n * D + gl * 8);
    f32x4 o0 = __builtin_nontemporal_load(op);
    f32x4 o1 = __builtin_nontemporal_load(op + 1);
    o0 += accA * inv;
    o1 += accB * inv;
    __builtin_nontemporal_store(o0, op);
    __builtin_nontemporal_store(o1, op + 1);
}

extern "C" void kernel_launch(void* const* d_in, const int* in_sizes, int n_in,
                              void* d_out, int out_size, void* d_ws, size_t ws_size,
                              hipStream_t stream) {
    const float* h       = (const float*)d_in[0];
    const float* emb_rel = (const float*)d_in[1];
    const float* fc1     = (const float*)d_in[2];   // [D, 3D]
    const float* fc2     = (const float*)d_in[3];   // [1, D]
    const float* loopw   = (const float*)d_in[4];   // [D, D]
    const int*   esrc    = (const int*)d_in[5];
    const int*   edst    = (const int*)d_in[6];
    const int*   etyp    = (const int*)d_in[7];
    float* out = (float*)d_out;
    float* ws  = (float*)d_ws;

    float*    w       = ws + OFF_W;
    float*    s1      = ws + OFF_S1;
    float*    s2      = ws + OFF_S2;
    float*    s3      = ws + OFF_S3;
    int*      counts  = (int*)(ws + OFF_COUNTS);
    unsigned* csr     = (unsigned*)(ws + OFF_CSR);
    u16*      hb      = (u16*)(ws + OFF_HB);

    // 1: MFMA self-loop GEMM (writes out + hb) + zero counters + w vector
    k_prep<<<GEMM_BLOCKS + ZERO_BLOCKS + 1, 256, 0, stream>>>(
        fc1, fc2, loopw, h, w, counts, hb, out);

    // 2: fused atomic CSR fill (8 edges/thread) + scores from bf16 hb
    k_fused<<<FILL_BLOCKS + SCORE_BLOCKS, 256, 0, stream>>>(
        esrc, edst, etyp, counts, csr, hb, emb_rel, w, s1, s2, s3);

    // 3: single-pass softmax gather (non-temporal RMW out)
    k_gather<<<(N_NODES * 16 + 255) / 256, 256, 0, stream>>>(
        hb, counts, csr, s1, s2, s3, out);
}